// Round 11
// baseline (1973.812 us; speedup 1.0000x reference)
//
#include <hip/hip_runtime.h>

// SparseCoding fused persistent kernel, fp32 VALU (R11).
// Arithmetic chains bit-identical to R1/R9 (absmax must stay 4.882812e-4).
// R10 post-mortem: __launch_bounds__(256,4) forced 64 VGPRs < ~96 live state
// -> scratch spill (WRITE_SIZE 65.5->89.7 MB). R11 re-decomposes so state
// fits naturally:
//  - 512 threads/block, RTILE=16 rows. Phase 2: one COLUMN per thread
//    (acc[16], a1[16], a2[16], x[16] regs). Phase 1: 4 rows x 1 col/thread.
//  - __launch_bounds__(512,6): 85-VGPR cap, 24 waves/CU, no spill.
//  - x kept in registers for update (no LDS x re-read); x_lds written only
//    for phase 1's broadcast reads. Zero-init dropped (update fully rewrites).
//  - step-0 mm1 skipped: x0=0 -> d0 = 0-inp bit-exactly (-5% FLOP, -1 phase).
//  - W4/Wt4 packs kept from R10 (coalesced dwordx4 loads, no addr math).

#define BSZ   32768
#define DIN   128
#define DOUT  512
#define RTILE 16
#define NSTEP 10
#define NT    512
#define NBLOCKS (BSZ / RTILE)   // 2048

// pack both layouts (one-time, 256 KB each into ws)
__global__ void sc_pack(const float* __restrict__ W, float* __restrict__ W4,
                        float* __restrict__ Wt4) {
    const int tid = blockIdx.x * blockDim.x + threadIdx.x;  // 0..65535
    const int j = tid >> 7;      // 0..511 (coalesced read of W row-major)
    const int i = tid & 127;     // 0..127
    const float v = W[j * DIN + i];
    W4 [(j >> 2) * 512  + i * 4 + (j & 3)] = v;   // [j/4][i][j%4]
    Wt4[(i >> 2) * 2048 + j * 4 + (i & 3)] = v;   // [i/4][j][i%4]
}

__global__ __launch_bounds__(NT, 6)
void sc_fused(const float* __restrict__ inp, const float4* __restrict__ W4,
              const float4* __restrict__ Wt4, float* __restrict__ out)
{
    __shared__ float x_lds[RTILE][DOUT];    // 32 KB
    __shared__ float d_lds[RTILE][DIN];     //  8 KB  (total 40 KB)

    const int t = threadIdx.x;
    const int row0 = blockIdx.x * RTILE;

    const int i_p1 = t & 127;        // phase-1 column (0..127)
    const int rg   = (t >> 7) * 4;   // phase-1 row group {0,4,8,12}
    const int j0   = t;              // phase-2/update column (0..511)

    // phase-2 per-thread state: one column, 16 rows
    float xs[RTILE], a1[RTILE], a2[RTILE];
#pragma unroll
    for (int r = 0; r < RTILE; ++r) { xs[r] = 0.f; a1[r] = 0.f; a2[r] = 0.f; }

    // inp values this thread needs in phase 1 (registers)
    float inr[4];
#pragma unroll
    for (int rr = 0; rr < 4; ++rr)
        inr[rr] = inp[(row0 + rg + rr) * DIN + i_p1];

    // thread-fixed base pointers
    const float4* __restrict__ w4p  = W4 + i_p1;    // + jb*128
    const float4* __restrict__ wt4p = Wt4 + j0;     // + ib*512

    for (int step = 0; step < NSTEP; ++step) {
        // ---- phase 1: d = x @ W - inp ----
        if (step == 0) {
            // x0 = 0: acc chain is exactly 0 -> d = 0 - inp (bit-identical)
#pragma unroll
            for (int rr = 0; rr < 4; ++rr)
                d_lds[rg + rr][i_p1] = 0.0f - inr[rr];
        } else {
            float acc[4];
#pragma unroll
            for (int rr = 0; rr < 4; ++rr) acc[rr] = 0.f;

#pragma unroll 2
            for (int jb = 0; jb < DOUT / 4; ++jb) {
                const float4 wv = w4p[jb * 128];   // W[4jb..4jb+3][i_p1]
#pragma unroll
                for (int rr = 0; rr < 4; ++rr) {
                    const float4 xv = *(const float4*)&x_lds[rg + rr][jb * 4];
                    acc[rr] = fmaf(xv.x, wv.x, acc[rr]);
                    acc[rr] = fmaf(xv.y, wv.y, acc[rr]);
                    acc[rr] = fmaf(xv.z, wv.z, acc[rr]);
                    acc[rr] = fmaf(xv.w, wv.w, acc[rr]);
                }
            }
#pragma unroll
            for (int rr = 0; rr < 4; ++rr)
                d_lds[rg + rr][i_p1] = acc[rr] - inr[rr];
        }
        __syncthreads();

        // ---- phase 2: gacc = d @ W^T (one column j0 per thread) ----
        {
            float acc2[RTILE];
#pragma unroll
            for (int r = 0; r < RTILE; ++r) acc2[r] = 0.f;

#pragma unroll 2
            for (int ib = 0; ib < DIN / 4; ++ib) {
                const float4 wq = wt4p[ib * 512];   // W[j0][4ib..4ib+3]
#pragma unroll
                for (int r = 0; r < RTILE; ++r) {
                    const float4 dv = *(const float4*)&d_lds[r][ib * 4];
                    acc2[r] = fmaf(dv.x, wq.x, acc2[r]);
                    acc2[r] = fmaf(dv.y, wq.y, acc2[r]);
                    acc2[r] = fmaf(dv.z, wq.z, acc2[r]);
                    acc2[r] = fmaf(dv.w, wq.w, acc2[r]);
                }
            }

            // RMSProp + momentum update (x in registers), write x_lds for
            // phase 1 of the next step
#pragma unroll
            for (int r = 0; r < RTILE; ++r) {
                const float xv  = xs[r];
                const float g   = 2.f * acc2[r] + 0.1f * xv * rsqrtf(xv * xv + 1e-6f);
                const float na1 = 0.9f * a1[r] + 0.1f * g * g;
                a1[r] = na1;
                const float upd = 0.001f * g * rsqrtf(na1 + 1e-8f);
                const float na2 = 0.9f * a2[r] - upd;
                a2[r] = na2;
                const float xn = xv + 0.9f * na2 - upd;
                xs[r] = xn;
                x_lds[r][j0] = xn;
            }
            __syncthreads();
        }
    }

    // write final x (coalesced; x_lds holds the final state)
    for (int k = t; k < RTILE * DOUT; k += NT)
        out[row0 * DOUT + k] = (&x_lds[0][0])[k];
}

extern "C" void kernel_launch(void* const* d_in, const int* in_sizes, int n_in,
                              void* d_out, int out_size, void* d_ws, size_t ws_size,
                              hipStream_t stream) {
    const float* inputs = (const float*)d_in[0];
    const float* W      = (const float*)d_in[1];
    float* out          = (float*)d_out;
    float* W4           = (float*)d_ws;               // 256 KB
    float* Wt4          = (float*)d_ws + 65536;       // 256 KB

    sc_pack<<<dim3(256), dim3(256), 0, stream>>>(W, W4, Wt4);
    sc_fused<<<dim3(NBLOCKS), dim3(NT), 0, stream>>>(inputs, (const float4*)W4,
                                                     (const float4*)Wt4, out);
}

// Round 12
// 1798.006 us; speedup vs baseline: 1.0978x; 1.0978x over previous
//
#include <hip/hip_runtime.h>

// SparseCoding fused persistent kernel, fp32 VALU (R12 = R9 shape + safe cuts).
// Arithmetic chains bit-identical to R1/R9 (absmax must stay 4.882812e-4).
// R10/R11 lesson: __launch_bounds__ min-waves beyond live-state capacity =>
// scratch spill (R10: 64 VGPR cap, +24MB writes; R11: 40 VGPR cap, +1GB).
// R12 keeps R9's proven-non-spilling shape: 256 threads, (256,3), 84 VGPR.
// Changes vs R9 (none touch an fmaf chain):
//  - phase 1 = 4 rows x 2 cols per thread (was 8x1): halves ds_read_b128 per
//    FMA (4 per 32 FMA); acc stays 8 regs.
//  - W4 pack [j/4][i][j%4]: one dwordx4 per (4j, col); Wt4 pack [i/4][j][i%4]
//    for phase 2 (both verified bit-exact in R10).
//  - step-0 phase 1 skipped: x0=0 -> acc == +0.0 exactly -> d0 = 0-inp.
//    Step-0 update uses literal xv=+0.0f (same chain); x zero-init dropped.
//  - inp in LDS (R9-style) to stay off the 84-VGPR cliff. LDS 48KB, 3 blk/CU.

#define BSZ   32768
#define DIN   128
#define DOUT  512
#define RTILE 16
#define NSTEP 10
#define NT    256
#define NBLOCKS (BSZ / RTILE)   // 2048

// pack both layouts (one-time, 256 KB each into ws)
__global__ void sc_pack(const float* __restrict__ W, float* __restrict__ W4,
                        float* __restrict__ Wt4) {
    const int tid = blockIdx.x * blockDim.x + threadIdx.x;  // 0..65535
    const int j = tid >> 7;      // 0..511 (coalesced read of W row-major)
    const int i = tid & 127;     // 0..127
    const float v = W[j * DIN + i];
    W4 [(j >> 2) * 512  + i * 4 + (j & 3)] = v;   // [j/4][i][j%4]
    Wt4[(i >> 2) * 2048 + j * 4 + (i & 3)] = v;   // [i/4][j][i%4]
}

__global__ __launch_bounds__(NT, 3)
void sc_fused(const float* __restrict__ inp, const float4* __restrict__ W4,
              const float4* __restrict__ Wt4, float* __restrict__ out)
{
    __shared__ float x_lds[RTILE][DOUT];    // 32 KB
    __shared__ float d_lds[RTILE][DIN];     //  8 KB
    __shared__ float inp_lds[RTILE][DIN];   //  8 KB  (48 KB total, 3 blk/CU)

    const int t = threadIdx.x;
    const int row0 = blockIdx.x * RTILE;

    const int ic = (t & 63) * 2;     // phase-1 column pair (0..126)
    const int rg = (t >> 6) * 4;     // phase-1 row group {0,4,8,12}
    const int j0 = 2 * t;            // phase-2/update column pair (0..510)

    // Per-thread RMSProp state (phase-2 mapping: 16 rows x 2 cols)
    float a1[RTILE][2];
    float a2[RTILE][2];
#pragma unroll
    for (int r = 0; r < RTILE; ++r) {
        a1[r][0] = a1[r][1] = 0.f;
        a2[r][0] = a2[r][1] = 0.f;
    }

    // load inputs tile (coalesced)
    for (int k = t; k < RTILE * DIN; k += NT)
        (&inp_lds[0][0])[k] = inp[row0 * DIN + k];
    __syncthreads();

    // thread-fixed base pointers (float4-granular packed panels)
    const float4* __restrict__ w4a  = W4 + ic;        // + jb*128 -> W[4jb+q][ic]
    const float4* __restrict__ w4b  = W4 + ic + 1;    // + jb*128 -> W[4jb+q][ic+1]
    const float4* __restrict__ wt4p = Wt4 + j0;       // + ib*512 (+1)

    for (int step = 0; step < NSTEP; ++step) {
        // ---- phase 1: d = x @ W - inp ----
        if (step == 0) {
            // x0 = 0: R1's acc chain is exactly +0.0 -> d = 0 - inp (bit-exact)
#pragma unroll
            for (int rr = 0; rr < 4; ++rr) {
                d_lds[rg + rr][ic + 0] = 0.0f - inp_lds[rg + rr][ic + 0];
                d_lds[rg + rr][ic + 1] = 0.0f - inp_lds[rg + rr][ic + 1];
            }
        } else {
            float acc[4][2];
#pragma unroll
            for (int rr = 0; rr < 4; ++rr) acc[rr][0] = acc[rr][1] = 0.f;

#pragma unroll 2
            for (int jb = 0; jb < DOUT / 4; ++jb) {
                const float4 wa = w4a[jb * 128];   // W[4jb..4jb+3][ic]
                const float4 wb = w4b[jb * 128];   // W[4jb..4jb+3][ic+1]
#pragma unroll
                for (int rr = 0; rr < 4; ++rr) {
                    const float4 xv = *(const float4*)&x_lds[rg + rr][jb * 4];  // broadcast
                    acc[rr][0] = fmaf(xv.x, wa.x, acc[rr][0]);
                    acc[rr][0] = fmaf(xv.y, wa.y, acc[rr][0]);
                    acc[rr][0] = fmaf(xv.z, wa.z, acc[rr][0]);
                    acc[rr][0] = fmaf(xv.w, wa.w, acc[rr][0]);
                    acc[rr][1] = fmaf(xv.x, wb.x, acc[rr][1]);
                    acc[rr][1] = fmaf(xv.y, wb.y, acc[rr][1]);
                    acc[rr][1] = fmaf(xv.z, wb.z, acc[rr][1]);
                    acc[rr][1] = fmaf(xv.w, wb.w, acc[rr][1]);
                }
            }
#pragma unroll
            for (int rr = 0; rr < 4; ++rr) {
                d_lds[rg + rr][ic + 0] = acc[rr][0] - inp_lds[rg + rr][ic + 0];
                d_lds[rg + rr][ic + 1] = acc[rr][1] - inp_lds[rg + rr][ic + 1];
            }
        }
        __syncthreads();

        // ---- phase 2: gacc = d @ W^T (16 rows x 2 cols per thread) ----
        {
            float acc2[RTILE][2];
#pragma unroll
            for (int r = 0; r < RTILE; ++r) acc2[r][0] = acc2[r][1] = 0.f;

#pragma unroll 2
            for (int ib = 0; ib < DIN / 4; ++ib) {
                const float4 qa = wt4p[ib * 512];       // W[j0][4ib..4ib+3]
                const float4 qb = wt4p[ib * 512 + 1];   // W[j0+1][4ib..4ib+3]
#pragma unroll
                for (int r = 0; r < RTILE; ++r) {
                    const float4 dv = *(const float4*)&d_lds[r][ib * 4];  // broadcast
                    acc2[r][0] = fmaf(dv.x, qa.x, acc2[r][0]);
                    acc2[r][0] = fmaf(dv.y, qa.y, acc2[r][0]);
                    acc2[r][0] = fmaf(dv.z, qa.z, acc2[r][0]);
                    acc2[r][0] = fmaf(dv.w, qa.w, acc2[r][0]);
                    acc2[r][1] = fmaf(dv.x, qb.x, acc2[r][1]);
                    acc2[r][1] = fmaf(dv.y, qb.y, acc2[r][1]);
                    acc2[r][1] = fmaf(dv.z, qb.z, acc2[r][1]);
                    acc2[r][1] = fmaf(dv.w, qb.w, acc2[r][1]);
                }
            }

            // RMSProp + momentum update (identical chains; step-0 xv = +0.0f)
#pragma unroll
            for (int r = 0; r < RTILE; ++r) {
#pragma unroll
                for (int c = 0; c < 2; ++c) {
                    const float xv  = (step == 0) ? 0.0f : x_lds[r][j0 + c];
                    const float g   = 2.f * acc2[r][c] + 0.1f * xv * rsqrtf(xv * xv + 1e-6f);
                    const float na1 = 0.9f * a1[r][c] + 0.1f * g * g;
                    a1[r][c] = na1;
                    const float upd = 0.001f * g * rsqrtf(na1 + 1e-8f);
                    const float na2 = 0.9f * a2[r][c] - upd;
                    a2[r][c] = na2;
                    x_lds[r][j0 + c] = xv + 0.9f * na2 - upd;
                }
            }
            __syncthreads();
        }
    }

    // write final x (coalesced)
    for (int k = t; k < RTILE * DOUT; k += NT)
        out[row0 * DOUT + k] = (&x_lds[0][0])[k];
}

extern "C" void kernel_launch(void* const* d_in, const int* in_sizes, int n_in,
                              void* d_out, int out_size, void* d_ws, size_t ws_size,
                              hipStream_t stream) {
    const float* inputs = (const float*)d_in[0];
    const float* W      = (const float*)d_in[1];
    float* out          = (float*)d_out;
    float* W4           = (float*)d_ws;               // 256 KB
    float* Wt4          = (float*)d_ws + 65536;       // 256 KB

    sc_pack<<<dim3(256), dim3(256), 0, stream>>>(W, W4, Wt4);
    sc_fused<<<dim3(NBLOCKS), dim3(NT), 0, stream>>>(inputs, (const float4*)W4,
                                                     (const float4*)Wt4, out);
}